// Round 8
// baseline (42.601 us; speedup 1.0000x reference)
//
#include <hip/hip_runtime.h>
#include <hip/hip_bf16.h>

typedef __attribute__((ext_vector_type(8))) short bf16x8;
typedef __attribute__((ext_vector_type(4))) float f32x4;

#define NPIX 6272          // 2*56*56
#define HW 56
#define HEADS 8
#define HD 32
#define KW 7
#define DIM 256
#define UK 112             // union keys: 8 rows x 14 cols
#define UKP 128            // padded keys
#define NX (NPIX * DIM)    // 1605632

__device__ inline short f2bf(float f) {
    __hip_bfloat16 h = __float2bfloat16(f);
    return *(short*)&h;
}
__device__ inline float bf2f(short u) {
    union { unsigned int i; float f; } x;
    x.i = ((unsigned int)(unsigned short)u) << 16;
    return x.f;
}
__device__ inline bf16x8 pack8(float4 f0, float4 f1) {
    bf16x8 v;
    v[0]=f2bf(f0.x); v[1]=f2bf(f0.y); v[2]=f2bf(f0.z); v[3]=f2bf(f0.w);
    v[4]=f2bf(f1.x); v[5]=f2bf(f1.y); v[6]=f2bf(f1.z); v[7]=f2bf(f1.w);
    return v;
}

// ---------------- Projection GEMM (fused f32->bf16): Y = X @ W^T + b --------
// grid (49, 4, 3): 128-row x 64-col tiles; each wave owns 2 row-tiles (M=32)
// sharing every W B-fragment. W staged in LDS (bf16, swizzled); X converted
// inline. All global loads batched ahead of dependent ops.
__global__ __launch_bounds__(256, 3) void proj_kernel(
    const float* __restrict__ X,
    const float* __restrict__ Wq, const float* __restrict__ Wk, const float* __restrict__ Wv,
    const float* __restrict__ Bq, const float* __restrict__ Bk, const float* __restrict__ Bv,
    __hip_bfloat16* __restrict__ Qo, __hip_bfloat16* __restrict__ Ko, __hip_bfloat16* __restrict__ Vo)
{
    __shared__ short Wsh[64 * 256];   // 32KB, byte ^= ((col&31)<<4)

    const int tid  = threadIdx.x;
    const int wave = tid >> 6;
    const int lane = tid & 63;
    const int l15  = lane & 15;
    const int hi   = lane >> 4;

    const float* W; const float* Bi; __hip_bfloat16* Y; float scale;
    if (blockIdx.z == 0)      { W = Wq; Bi = Bq; Y = Qo; scale = 0.17677669529663687f; }
    else if (blockIdx.z == 1) { W = Wk; Bi = Bk; Y = Ko; scale = 1.0f; }
    else                      { W = Wv; Bi = Bv; Y = Vo; scale = 1.0f; }

    // ---- issue W staging loads (16 float4) ----
    const int col = tid >> 2;
    const int k0  = (tid & 3) * 64;
    const float* wsrc = W + (size_t)(blockIdx.y * 64 + col) * DIM + k0;
    float4 wf[16];
    #pragma unroll
    for (int m = 0; m < 16; ++m) wf[m] = *(const float4*)(wsrc + m * 4);

    // ---- issue A row-tile-0 loads (16 float4) ----
    const int rbase = blockIdx.x * 128 + wave * 32;
    const float* x0 = X + (size_t)(rbase + l15) * DIM;
    const float* x1 = X + (size_t)(rbase + 16 + l15) * DIM;
    float4 a0f[16];
    #pragma unroll
    for (int m = 0; m < 16; ++m)
        a0f[m] = *(const float4*)(x0 + (m >> 1) * 32 + hi * 8 + (m & 1) * 4);

    // ---- cvt W -> LDS swizzled ----
    {
        char* row = (char*)Wsh + col * 512;
        const int swz = (col & 31) << 4;
        #pragma unroll
        for (int m = 0; m < 8; ++m)
            *(bf16x8*)(row + ((2 * (k0 + m * 8)) ^ swz)) = pack8(wf[2*m], wf[2*m+1]);
    }

    // ---- issue A row-tile-1 loads; cvt A0 ----
    float4 a1f[16];
    #pragma unroll
    for (int m = 0; m < 16; ++m)
        a1f[m] = *(const float4*)(x1 + (m >> 1) * 32 + hi * 8 + (m & 1) * 4);

    bf16x8 a0[8], a1[8];
    #pragma unroll
    for (int kk = 0; kk < 8; ++kk) a0[kk] = pack8(a0f[2*kk], a0f[2*kk+1]);

    __syncthreads();

    #pragma unroll
    for (int kk = 0; kk < 8; ++kk) a1[kk] = pack8(a1f[2*kk], a1f[2*kk+1]);

    f32x4 acc0[4], acc1[4];
    #pragma unroll
    for (int c = 0; c < 4; ++c) {
        acc0[c] = (f32x4){0.f, 0.f, 0.f, 0.f};
        acc1[c] = (f32x4){0.f, 0.f, 0.f, 0.f};
    }

    #pragma unroll
    for (int kk = 0; kk < 8; ++kk) {
        #pragma unroll
        for (int c = 0; c < 4; ++c) {
            const int bcol = c * 16 + l15;
            bf16x8 b = *(const bf16x8*)((char*)Wsh + bcol * 512 +
                                        ((kk * 64 + hi * 16) ^ ((bcol & 31) << 4)));
            acc0[c] = __builtin_amdgcn_mfma_f32_16x16x32_bf16(a0[kk], b, acc0[c], 0, 0, 0);
            acc1[c] = __builtin_amdgcn_mfma_f32_16x16x32_bf16(a1[kk], b, acc1[c], 0, 0, 0);
        }
    }

    #pragma unroll
    for (int c = 0; c < 4; ++c) {
        const int ocol = blockIdx.y * 64 + c * 16 + l15;
        const float bvv = Bi[ocol];
        #pragma unroll
        for (int r = 0; r < 4; ++r) {
            const int row = rbase + hi * 4 + r;
            Y[(size_t)row * DIM + ocol]        = __float2bfloat16((acc0[c][r] + bvv) * scale);
            Y[(size_t)(row + 16) * DIM + ocol] = __float2bfloat16((acc1[c][r] + bvv) * scale);
        }
    }
}

// ---------------- Neighborhood attention, MFMA-tiled, head-split ------------
// (unchanged from round 7 — isolates this round's proj/launch changes)
__global__ __launch_bounds__(256, 3) void nattn_kernel(
    const __hip_bfloat16* __restrict__ Qg,   // [NPIX][256] bf16 ws
    const __hip_bfloat16* __restrict__ Kg,
    const __hip_bfloat16* __restrict__ Vg,
    const float* __restrict__ rpb,           // [8][13][13] f32
    float* __restrict__ out)                 // [NPIX][256] f32
{
    __shared__ short VshT[128 * UKP];            // 32768 B: [d'][key], byte ^= ((d'&7)<<4)
    __shared__ short Psh[4 * 16 * UKP];          // 16384 B: byte ^= (pix<<4)
    __shared__ __align__(16) short rpbs[8 * 169]; // 2704 B bf16

    const int tid  = threadIdx.x;
    const int wv   = tid >> 6;
    const int lane = tid & 63;
    const int l15  = lane & 15;
    const int hi   = lane >> 4;

    const int jt = blockIdx.x;               // 0..6
    const int ip = blockIdx.y >> 1;          // 0..27
    const int hg = blockIdx.y & 1;           // head group
    const int bz = blockIdx.z;
    const int i0 = 2 * ip;
    const int j0 = jt * 8;
    const int r0 = min(max(i0 - 3, 0), HW - KW);
    const int c0 = min(max(j0 - 3, 0), HW - KW);

    const int h = hg * 4 + wv;               // this wave's head

    // ---- batch-issue ALL staging global loads ------------------------------
    const int k2   = tid & 63;               // key pair index
    const int dblk = tid >> 6;               // 0..3 -> dims dblk*32..+31
    const int keyL = 2 * k2, keyR = 2 * k2 + 1;
    const int aL = keyL / 14, cL = keyL - aL * 14;
    const int aR = keyR / 14, cR = keyR - aR * 14;
    const int giL = min(r0 + aL, HW - 1), gjL = min(c0 + cL, HW - 1);
    const int giR = min(r0 + aR, HW - 1), gjR = min(c0 + cR, HW - 1);
    const short* srcL = (const short*)Vg + ((size_t)((bz * HW + giL) * HW + gjL)) * DIM + hg * 128 + dblk * 32;
    const short* srcR = (const short*)Vg + ((size_t)((bz * HW + giR) * HW + gjR)) * DIM + hg * 128 + dblk * 32;
    bf16x8 vL[4], vR[4];
    #pragma unroll
    for (int m = 0; m < 4; ++m) {
        vL[m] = (keyL < UK) ? *(const bf16x8*)(srcL + m * 8) : (bf16x8){0,0,0,0,0,0,0,0};
        vR[m] = (keyR < UK) ? *(const bf16x8*)(srcR + m * 8) : (bf16x8){0,0,0,0,0,0,0,0};
    }

    const int qpix = (bz * HW + i0 + (l15 >> 3)) * HW + j0 + (l15 & 7);
    bf16x8 aq = *(const bf16x8*)((const short*)Qg + (size_t)qpix * DIM + h * HD + hi * 8);

    const float4* rpb4 = (const float4*)rpb;
    float4 rv0 = rpb4[tid];
    float4 rv1 = (tid < 338 - 256) ? rpb4[tid + 256] : (float4){0.f,0.f,0.f,0.f};

    // ---- LDS writes --------------------------------------------------------
    #pragma unroll
    for (int m = 0; m < 4; ++m) {
        #pragma unroll
        for (int e = 0; e < 8; ++e) {
            const int d = dblk * 32 + m * 8 + e;          // d&7 == e
            const int w = ((int)(unsigned short)vL[m][e]) | ((int)vR[m][e] << 16);
            *(int*)((char*)VshT + d * 256 + ((4 * k2) ^ (e << 4))) = w;
        }
    }
    *(short4*)(&rpbs[tid * 4]) = make_short4(f2bf(rv0.x), f2bf(rv0.y), f2bf(rv0.z), f2bf(rv0.w));
    if (tid < 338 - 256)
        *(short4*)(&rpbs[(tid + 256) * 4]) = make_short4(f2bf(rv1.x), f2bf(rv1.y), f2bf(rv1.z), f2bf(rv1.w));
    {   // zero Psh keys 112..127 (swizzled), per wave region
        const int p = (lane >> 2) & 15, m4 = lane & 3;
        const int k = UK + m4 * 4;
        char* dst = (char*)Psh + (wv * 16 + p) * 256 + ((2 * k) ^ (p << 4));
        *(int2*)dst = make_int2(0, 0);
    }
    __syncthreads();

    int iv[4], jv[4], bb[4], uai[4], ucj[4];
    #pragma unroll
    for (int r = 0; r < 4; ++r) {
        const int p = hi * 4 + r;
        iv[r] = i0 + (p >> 3);
        jv[r] = j0 + (p & 7);
        const int siv = min(max(iv[r] - 3, 0), HW - KW);
        const int sjv = min(max(jv[r] - 3, 0), HW - KW);
        bb[r]  = (r0 - iv[r] + 6) * 13 + (c0 - jv[r] + 6);
        uai[r] = siv - r0;
        ucj[r] = sjv - c0;
    }
    const f32x4 zf = {0.f, 0.f, 0.f, 0.f};

    // scores: batch-issue 7 K B-frag loads, then 7 MFMAs
    f32x4 sacc[7];
    {
        bf16x8 kb[7];
        #pragma unroll
        for (int t = 0; t < 7; ++t) {
            const int key = t * 16 + l15;
            const int a = key / 14, c = key - a * 14;
            const int gi = min(r0 + a, HW - 1), gj = min(c0 + c, HW - 1);
            kb[t] = *(const bf16x8*)((const short*)Kg +
                     ((size_t)((bz * HW + gi) * HW + gj)) * DIM + h * HD + hi * 8);
        }
        #pragma unroll
        for (int t = 0; t < 7; ++t)
            sacc[t] = __builtin_amdgcn_mfma_f32_16x16x32_bf16(aq, kb[t], zf, 0, 0, 0);
    }

    // bias + mask -> sc[r][t]
    const short* rbh = rpbs + h * 169;
    int aA[7], cA[7], a13[7];
    #pragma unroll
    for (int t = 0; t < 7; ++t) {
        const int key = t * 16 + l15;
        aA[t] = key / 14;
        cA[t] = key - aA[t] * 14;
        a13[t] = aA[t] * 13 + cA[t];
    }
    float sc[4][7];
    #pragma unroll
    for (int t = 0; t < 7; ++t) {
        #pragma unroll
        for (int r = 0; r < 4; ++r) {
            const bool ok = ((unsigned)(aA[t] - uai[r]) <= 6u) &
                            ((unsigned)(cA[t] - ucj[r]) <= 6u);
            const float s = sacc[t][r] + bf2f(rbh[bb[r] + a13[t]]);
            sc[r][t] = ok ? s : -1e30f;
        }
    }

    // row max + exp + P store + sum
    float sm[4];
    #pragma unroll
    for (int r = 0; r < 4; ++r) {
        float m = sc[r][0];
        #pragma unroll
        for (int t = 1; t < 7; ++t) m = fmaxf(m, sc[r][t]);
        m = fmaxf(m, __shfl_xor(m, 1));
        m = fmaxf(m, __shfl_xor(m, 2));
        m = fmaxf(m, __shfl_xor(m, 4));
        m = fmaxf(m, __shfl_xor(m, 8));
        const int pix = hi * 4 + r;
        char* prow = (char*)Psh + (wv * 16 + pix) * 256;
        const int pswz = pix << 4;
        float s = 0.f;
        #pragma unroll
        for (int t = 0; t < 7; ++t) {
            const float e = __expf(sc[r][t] - m);
            s += e;
            const int key = t * 16 + l15;
            *(short*)(prow + ((2 * key) ^ pswz)) = f2bf(e);
        }
        s += __shfl_xor(s, 1);
        s += __shfl_xor(s, 2);
        s += __shfl_xor(s, 4);
        s += __shfl_xor(s, 8);
        sm[r] = s;
    }

    // PV: 4 ksteps x 2 dim-tiles
    const int d0 = wv * 32 + l15;
    f32x4 o0 = zf, o1 = zf;
    #pragma unroll
    for (int kk = 0; kk < 4; ++kk) {
        bf16x8 pa = *(const bf16x8*)((char*)Psh + (wv * 16 + l15) * 256 +
                                     ((kk * 64 + hi * 16) ^ (l15 << 4)));
        const int koff = (kk * 64 + hi * 16) ^ ((l15 & 7) << 4);
        bf16x8 vb0 = *(const bf16x8*)((char*)VshT + d0 * 256 + koff);
        bf16x8 vb1 = *(const bf16x8*)((char*)VshT + (d0 + 16) * 256 + koff);
        o0 = __builtin_amdgcn_mfma_f32_16x16x32_bf16(pa, vb0, o0, 0, 0, 0);
        o1 = __builtin_amdgcn_mfma_f32_16x16x32_bf16(pa, vb1, o1, 0, 0, 0);
    }

    // epilogue
    #pragma unroll
    for (int r = 0; r < 4; ++r) {
        const float inv = 1.f / sm[r];
        const int pg = (bz * HW + iv[r]) * HW + jv[r];
        out[(size_t)pg * DIM + h * HD + l15]      = o0[r] * inv;
        out[(size_t)pg * DIM + h * HD + 16 + l15] = o1[r] * inv;
    }
}

extern "C" void kernel_launch(void* const* d_in, const int* in_sizes, int n_in,
                              void* d_out, int out_size, void* d_ws, size_t ws_size,
                              hipStream_t stream) {
    const float* hs = (const float*)d_in[0];
    const float* wq = (const float*)d_in[1];
    const float* bq = (const float*)d_in[2];
    const float* wk = (const float*)d_in[3];
    const float* bk = (const float*)d_in[4];
    const float* wv = (const float*)d_in[5];
    const float* bv = (const float*)d_in[6];
    const float* rpb = (const float*)d_in[7];

    short* Q = (short*)d_ws;
    short* K = Q + (size_t)NX;
    short* V = K + (size_t)NX;

    proj_kernel<<<dim3(NPIX / 128, 4, 3), 256, 0, stream>>>(
        hs, wq, wk, wv, bq, bk, bv,
        (__hip_bfloat16*)Q, (__hip_bfloat16*)K, (__hip_bfloat16*)V);

    nattn_kernel<<<dim3(7, 56, 2), 256, 0, stream>>>(
        (const __hip_bfloat16*)Q, (const __hip_bfloat16*)K, (const __hip_bfloat16*)V,
        rpb, (float*)d_out);
}

// Round 9
// 36.870 us; speedup vs baseline: 1.1554x; 1.1554x over previous
//
#include <hip/hip_runtime.h>
#include <hip/hip_bf16.h>

typedef __attribute__((ext_vector_type(8))) short bf16x8;
typedef __attribute__((ext_vector_type(4))) float f32x4;

#define NPIX 6272          // 2*56*56
#define HW 56
#define HEADS 8
#define HD 32
#define KW 7
#define DIM 256
#define GDIM 768           // Q|K|V interleaved row stride
#define UK 112             // union keys: 8 rows x 14 cols
#define UKP 128            // padded keys
#define NX (NPIX * DIM)    // 1605632
#define NW (DIM * DIM)     // 65536

__device__ inline short f2bf(float f) {
    __hip_bfloat16 h = __float2bfloat16(f);
    return *(short*)&h;
}
__device__ inline float bf2f(short u) {
    union { unsigned int i; float f; } x;
    x.i = ((unsigned int)(unsigned short)u) << 16;
    return x.f;
}

__device__ __forceinline__ void gl_lds16(const short* g, short* l) {
    __builtin_amdgcn_global_load_lds(
        (const __attribute__((address_space(1))) unsigned int*)g,
        (__attribute__((address_space(3))) unsigned int*)l,
        16, 0, 0);
}

// ---------------- f32 -> bf16 conversion pre-pass ---------------------------
// Xb[6272][256] and Wcat[768][256] (= Wq|Wk|Wv stacked), all bf16.
__global__ __launch_bounds__(256) void cvt_kernel(
    const float* __restrict__ X,
    const float* __restrict__ Wq, const float* __restrict__ Wk, const float* __restrict__ Wv,
    short* __restrict__ Xb, short* __restrict__ Wcb)
{
    const size_t e0 = ((size_t)blockIdx.x * 256 + threadIdx.x) * 8;
    const float* src; short* dst; size_t off;
    if (e0 < NX)                { src = X;  dst = Xb;        off = e0; }
    else if (e0 < NX + NW)      { src = Wq; dst = Wcb;       off = e0 - NX; }
    else if (e0 < NX + 2 * NW)  { src = Wk; dst = Wcb + NW;  off = e0 - NX - NW; }
    else                        { src = Wv; dst = Wcb + 2*NW; off = e0 - NX - 2 * NW; }
    float4 f0 = *(const float4*)(src + off);
    float4 f1 = *(const float4*)(src + off + 4);
    bf16x8 v;
    v[0]=f2bf(f0.x); v[1]=f2bf(f0.y); v[2]=f2bf(f0.z); v[3]=f2bf(f0.w);
    v[4]=f2bf(f1.x); v[5]=f2bf(f1.y); v[6]=f2bf(f1.z); v[7]=f2bf(f1.w);
    *(bf16x8*)(dst + off) = v;
}

// ---------------- Projection GEMM: Y[6272][768] = Xb @ Wcat^T + b -----------
// grid (98, 12): 64-row x 64-col tiles, K=256 single-shot.
// A and B tiles staged via global_load_lds (16B/lane, coalesced) with
// inverse-swizzled SOURCE + linear LDS; fragment ds_reads apply the same
// XOR swizzle -> conflict-free (rule #21 both-sides pattern).
__global__ __launch_bounds__(256, 2) void proj_kernel(
    const short* __restrict__ Xb,     // [6272][256] bf16
    const short* __restrict__ Wcb,    // [768][256] bf16
    const float* __restrict__ Bq, const float* __restrict__ Bk, const float* __restrict__ Bv,
    short* __restrict__ Y)            // [6272][768] bf16
{
    __shared__ short Ash[64 * 256];   // 32KB: [row][512B], chunk p holds global chunk p^(row&7)
    __shared__ short Bsh[64 * 256];   // 32KB: same scheme over W rows (= out cols)

    const int tid  = threadIdx.x;
    const int wave = tid >> 6;
    const int lane = tid & 63;
    const int l15  = lane & 15;
    const int hi   = lane >> 4;

    const int brow = blockIdx.x * 64;
    const int bcol = blockIdx.y * 64;

    // ---- stage A and B tiles: 8 slots each per thread ----
    #pragma unroll
    for (int i = 0; i < 8; ++i) {
        const int slot = tid + i * 256;          // 0..2047
        const int row  = slot >> 5;              // 0..63
        const int p    = slot & 31;              // 16B chunk within 512B row
        const int goff = ((p ^ (row & 7)) << 3); // elements (16B = 8 shorts)
        gl_lds16(Xb  + (size_t)(brow + row) * DIM + goff, Ash + slot * 8);
        gl_lds16(Wcb + (size_t)(bcol + row) * DIM + goff, Bsh + slot * 8);
    }
    __syncthreads();

    f32x4 acc[4];
    #pragma unroll
    for (int c = 0; c < 4; ++c) acc[c] = (f32x4){0.f, 0.f, 0.f, 0.f};

    const int arow = wave * 16 + l15;
    #pragma unroll
    for (int kk = 0; kk < 8; ++kk) {
        const int ch = kk * 4 + hi;              // 16B chunk index 0..31
        bf16x8 a = *(const bf16x8*)((char*)Ash + arow * 512 + ((ch ^ (arow & 7)) << 4));
        #pragma unroll
        for (int c = 0; c < 4; ++c) {
            const int bro = c * 16 + l15;
            bf16x8 b = *(const bf16x8*)((char*)Bsh + bro * 512 + ((ch ^ (bro & 7)) << 4));
            acc[c] = __builtin_amdgcn_mfma_f32_16x16x32_bf16(a, b, acc[c], 0, 0, 0);
        }
    }

    // epilogue: bias + scale (col tile never crosses a 256 boundary)
    const int z = blockIdx.y >> 2;
    const float* Bi = (z == 0) ? Bq : (z == 1) ? Bk : Bv;
    const float scale = (z == 0) ? 0.17677669529663687f : 1.0f;
    #pragma unroll
    for (int c = 0; c < 4; ++c) {
        const int ocol = bcol + c * 16 + l15;
        const float bvv = Bi[ocol & 255];
        #pragma unroll
        for (int r = 0; r < 4; ++r) {
            const int row = brow + wave * 16 + hi * 4 + r;
            Y[(size_t)row * GDIM + ocol] = f2bf((acc[c][r] + bvv) * scale);
        }
    }
}

// ---------------- Neighborhood attention (round-7 structure, Y strides) -----
__global__ __launch_bounds__(256, 3) void nattn_kernel(
    const short* __restrict__ Yg,            // [NPIX][768] bf16: Q|K|V
    const float* __restrict__ rpb,           // [8][13][13] f32
    float* __restrict__ out)                 // [NPIX][256] f32
{
    __shared__ short VshT[128 * UKP];            // 32768 B: [d'][key], byte ^= ((d'&7)<<4)
    __shared__ short Psh[4 * 16 * UKP];          // 16384 B: byte ^= (pix<<4)
    __shared__ __align__(16) short rpbs[8 * 169]; // 2704 B bf16

    const int tid  = threadIdx.x;
    const int wv   = tid >> 6;
    const int lane = tid & 63;
    const int l15  = lane & 15;
    const int hi   = lane >> 4;

    const int jt = blockIdx.x;               // 0..6
    const int ip = blockIdx.y >> 1;          // 0..27
    const int hg = blockIdx.y & 1;           // head group
    const int bz = blockIdx.z;
    const int i0 = 2 * ip;
    const int j0 = jt * 8;
    const int r0 = min(max(i0 - 3, 0), HW - KW);
    const int c0 = min(max(j0 - 3, 0), HW - KW);

    const int h = hg * 4 + wv;               // this wave's head

    // ---- batch-issue ALL staging global loads ------------------------------
    const int k2   = tid & 63;               // key pair index
    const int dblk = tid >> 6;               // 0..3 -> dims dblk*32..+31
    const int keyL = 2 * k2, keyR = 2 * k2 + 1;
    const int aL = keyL / 14, cL = keyL - aL * 14;
    const int aR = keyR / 14, cR = keyR - aR * 14;
    const int giL = min(r0 + aL, HW - 1), gjL = min(c0 + cL, HW - 1);
    const int giR = min(r0 + aR, HW - 1), gjR = min(c0 + cR, HW - 1);
    const short* srcL = Yg + (size_t)((bz * HW + giL) * HW + gjL) * GDIM + 512 + hg * 128 + dblk * 32;
    const short* srcR = Yg + (size_t)((bz * HW + giR) * HW + gjR) * GDIM + 512 + hg * 128 + dblk * 32;
    bf16x8 vL[4], vR[4];
    #pragma unroll
    for (int m = 0; m < 4; ++m) {
        vL[m] = (keyL < UK) ? *(const bf16x8*)(srcL + m * 8) : (bf16x8){0,0,0,0,0,0,0,0};
        vR[m] = (keyR < UK) ? *(const bf16x8*)(srcR + m * 8) : (bf16x8){0,0,0,0,0,0,0,0};
    }

    const int qpix = (bz * HW + i0 + (l15 >> 3)) * HW + j0 + (l15 & 7);
    bf16x8 aq = *(const bf16x8*)(Yg + (size_t)qpix * GDIM + h * HD + hi * 8);

    const float4* rpb4 = (const float4*)rpb;
    float4 rv0 = rpb4[tid];
    float4 rv1 = (tid < 338 - 256) ? rpb4[tid + 256] : (float4){0.f,0.f,0.f,0.f};

    // ---- LDS writes --------------------------------------------------------
    #pragma unroll
    for (int m = 0; m < 4; ++m) {
        #pragma unroll
        for (int e = 0; e < 8; ++e) {
            const int d = dblk * 32 + m * 8 + e;          // d&7 == e
            const int w = ((int)(unsigned short)vL[m][e]) | ((int)vR[m][e] << 16);
            *(int*)((char*)VshT + d * 256 + ((4 * k2) ^ (e << 4))) = w;
        }
    }
    *(short4*)(&rpbs[tid * 4]) = make_short4(f2bf(rv0.x), f2bf(rv0.y), f2bf(rv0.z), f2bf(rv0.w));
    if (tid < 338 - 256)
        *(short4*)(&rpbs[(tid + 256) * 4]) = make_short4(f2bf(rv1.x), f2bf(rv1.y), f2bf(rv1.z), f2bf(rv1.w));
    {   // zero Psh keys 112..127 (swizzled), per wave region
        const int p = (lane >> 2) & 15, m4 = lane & 3;
        const int k = UK + m4 * 4;
        char* dst = (char*)Psh + (wv * 16 + p) * 256 + ((2 * k) ^ (p << 4));
        *(int2*)dst = make_int2(0, 0);
    }
    __syncthreads();

    int iv[4], jv[4], bb[4], uai[4], ucj[4];
    #pragma unroll
    for (int r = 0; r < 4; ++r) {
        const int p = hi * 4 + r;
        iv[r] = i0 + (p >> 3);
        jv[r] = j0 + (p & 7);
        const int siv = min(max(iv[r] - 3, 0), HW - KW);
        const int sjv = min(max(jv[r] - 3, 0), HW - KW);
        bb[r]  = (r0 - iv[r] + 6) * 13 + (c0 - jv[r] + 6);
        uai[r] = siv - r0;
        ucj[r] = sjv - c0;
    }
    const f32x4 zf = {0.f, 0.f, 0.f, 0.f};

    // scores: batch-issue 7 K B-frag loads, then 7 MFMAs
    f32x4 sacc[7];
    {
        bf16x8 kb[7];
        #pragma unroll
        for (int t = 0; t < 7; ++t) {
            const int key = t * 16 + l15;
            const int a = key / 14, c = key - a * 14;
            const int gi = min(r0 + a, HW - 1), gj = min(c0 + c, HW - 1);
            kb[t] = *(const bf16x8*)(Yg + (size_t)((bz * HW + gi) * HW + gj) * GDIM +
                                     256 + h * HD + hi * 8);
        }
        #pragma unroll
        for (int t = 0; t < 7; ++t)
            sacc[t] = __builtin_amdgcn_mfma_f32_16x16x32_bf16(aq, kb[t], zf, 0, 0, 0);
    }

    // bias + mask -> sc[r][t]
    const short* rbh = rpbs + h * 169;
    int aA[7], cA[7], a13[7];
    #pragma unroll
    for (int t = 0; t < 7; ++t) {
        const int key = t * 16 + l15;
        aA[t] = key / 14;
        cA[t] = key - aA[t] * 14;
        a13[t] = aA[t] * 13 + cA[t];
    }
    float sc[4][7];
    #pragma unroll
    for (int t = 0; t < 7; ++t) {
        #pragma unroll
        for (int r = 0; r < 4; ++r) {
            const bool ok = ((unsigned)(aA[t] - uai[r]) <= 6u) &
                            ((unsigned)(cA[t] - ucj[r]) <= 6u);
            const float s = sacc[t][r] + bf2f(rbh[bb[r] + a13[t]]);
            sc[r][t] = ok ? s : -1e30f;
        }
    }

    // row max + exp + P store + sum
    float sm[4];
    #pragma unroll
    for (int r = 0; r < 4; ++r) {
        float m = sc[r][0];
        #pragma unroll
        for (int t = 1; t < 7; ++t) m = fmaxf(m, sc[r][t]);
        m = fmaxf(m, __shfl_xor(m, 1));
        m = fmaxf(m, __shfl_xor(m, 2));
        m = fmaxf(m, __shfl_xor(m, 4));
        m = fmaxf(m, __shfl_xor(m, 8));
        const int pix = hi * 4 + r;
        char* prow = (char*)Psh + (wv * 16 + pix) * 256;
        const int pswz = pix << 4;
        float s = 0.f;
        #pragma unroll
        for (int t = 0; t < 7; ++t) {
            const float e = __expf(sc[r][t] - m);
            s += e;
            const int key = t * 16 + l15;
            *(short*)(prow + ((2 * key) ^ pswz)) = f2bf(e);
        }
        s += __shfl_xor(s, 1);
        s += __shfl_xor(s, 2);
        s += __shfl_xor(s, 4);
        s += __shfl_xor(s, 8);
        sm[r] = s;
    }

    // PV: 4 ksteps x 2 dim-tiles
    const int d0 = wv * 32 + l15;
    f32x4 o0 = zf, o1 = zf;
    #pragma unroll
    for (int kk = 0; kk < 4; ++kk) {
        bf16x8 pa = *(const bf16x8*)((char*)Psh + (wv * 16 + l15) * 256 +
                                     ((kk * 64 + hi * 16) ^ (l15 << 4)));
        const int koff = (kk * 64 + hi * 16) ^ ((l15 & 7) << 4);
        bf16x8 vb0 = *(const bf16x8*)((char*)VshT + d0 * 256 + koff);
        bf16x8 vb1 = *(const bf16x8*)((char*)VshT + (d0 + 16) * 256 + koff);
        o0 = __builtin_amdgcn_mfma_f32_16x16x32_bf16(pa, vb0, o0, 0, 0, 0);
        o1 = __builtin_amdgcn_mfma_f32_16x16x32_bf16(pa, vb1, o1, 0, 0, 0);
    }

    // epilogue
    #pragma unroll
    for (int r = 0; r < 4; ++r) {
        const float inv = 1.f / sm[r];
        const int pg = (bz * HW + iv[r]) * HW + jv[r];
        out[(size_t)pg * DIM + h * HD + l15]      = o0[r] * inv;
        out[(size_t)pg * DIM + h * HD + 16 + l15] = o1[r] * inv;
    }
}

extern "C" void kernel_launch(void* const* d_in, const int* in_sizes, int n_in,
                              void* d_out, int out_size, void* d_ws, size_t ws_size,
                              hipStream_t stream) {
    const float* hs = (const float*)d_in[0];
    const float* wq = (const float*)d_in[1];
    const float* bq = (const float*)d_in[2];
    const float* wk = (const float*)d_in[3];
    const float* bk = (const float*)d_in[4];
    const float* wv = (const float*)d_in[5];
    const float* bv = (const float*)d_in[6];
    const float* rpb = (const float*)d_in[7];

    short* Y   = (short*)d_ws;                       // [6272][768]
    short* Xb  = Y + (size_t)NPIX * GDIM;            // [6272][256]
    short* Wcb = Xb + (size_t)NX;                    // [768][256]

    cvt_kernel<<<(NX + 3 * NW) / (256 * 8), 256, 0, stream>>>(hs, wq, wk, wv, Xb, Wcb);

    proj_kernel<<<dim3(NPIX / 64, 12), 256, 0, stream>>>(Xb, Wcb, bq, bk, bv, Y);

    nattn_kernel<<<dim3(7, 56, 2), 256, 0, stream>>>(Y, rpb, (float*)d_out);
}

// Round 10
// 32.798 us; speedup vs baseline: 1.2989x; 1.1242x over previous
//
#include <hip/hip_runtime.h>
#include <hip/hip_bf16.h>

typedef __attribute__((ext_vector_type(8))) short bf16x8;
typedef __attribute__((ext_vector_type(4))) float f32x4;

#define NPIX 6272          // 2*56*56
#define HW 56
#define HEADS 8
#define HD 32
#define KW 7
#define DIM 256
#define GDIM 768           // Q|K|V interleaved row stride
#define UK 112             // union keys: 8 rows x 14 cols
#define UKP 128            // padded keys
#define NX (NPIX * DIM)    // 1605632
#define NW (DIM * DIM)     // 65536

__device__ inline short f2bf(float f) {
    __hip_bfloat16 h = __float2bfloat16(f);
    return *(short*)&h;
}
__device__ inline float bf2f(short u) {
    union { unsigned int i; float f; } x;
    x.i = ((unsigned int)(unsigned short)u) << 16;
    return x.f;
}

__device__ __forceinline__ void gl_lds16(const short* g, short* l) {
    __builtin_amdgcn_global_load_lds(
        (const __attribute__((address_space(1))) unsigned int*)g,
        (__attribute__((address_space(3))) unsigned int*)l,
        16, 0, 0);
}

// ---------------- f32 -> bf16 conversion pre-pass ---------------------------
__global__ __launch_bounds__(256) void cvt_kernel(
    const float* __restrict__ X,
    const float* __restrict__ Wq, const float* __restrict__ Wk, const float* __restrict__ Wv,
    short* __restrict__ Xb, short* __restrict__ Wcb)
{
    const size_t e0 = ((size_t)blockIdx.x * 256 + threadIdx.x) * 8;
    const float* src; short* dst; size_t off;
    if (e0 < NX)                { src = X;  dst = Xb;        off = e0; }
    else if (e0 < NX + NW)      { src = Wq; dst = Wcb;       off = e0 - NX; }
    else if (e0 < NX + 2 * NW)  { src = Wk; dst = Wcb + NW;  off = e0 - NX - NW; }
    else                        { src = Wv; dst = Wcb + 2*NW; off = e0 - NX - 2 * NW; }
    float4 f0 = *(const float4*)(src + off);
    float4 f1 = *(const float4*)(src + off + 4);
    bf16x8 v;
    v[0]=f2bf(f0.x); v[1]=f2bf(f0.y); v[2]=f2bf(f0.z); v[3]=f2bf(f0.w);
    v[4]=f2bf(f1.x); v[5]=f2bf(f1.y); v[6]=f2bf(f1.z); v[7]=f2bf(f1.w);
    *(bf16x8*)(dst + off) = v;
}

// ---------------- Projection GEMM: Y[6272][768] = Xb @ Wcat^T + b -----------
// 1-D grid 1176 = 8 XCDs x 147: each XCD owns ~12 row-tiles x all 12 col-tiles
// (B matrix fully L2-resident per XCD; A tiles reused 12x in-XCD).
__global__ __launch_bounds__(256, 2) void proj_kernel(
    const short* __restrict__ Xb,     // [6272][256] bf16
    const short* __restrict__ Wcb,    // [768][256] bf16
    const float* __restrict__ Bq, const float* __restrict__ Bk, const float* __restrict__ Bv,
    short* __restrict__ Y)            // [6272][768] bf16
{
    __shared__ short Ash[64 * 256];   // 32KB: [row][512B], chunk p holds global chunk p^(row&7)
    __shared__ short Bsh[64 * 256];

    // XCD-aware bijective swizzle: 1176 = 8 * 147
    const int id   = blockIdx.x;
    const int flat = (id & 7) * 147 + (id >> 3);
    const int bx   = flat / 12;              // row tile 0..97
    const int by   = flat - bx * 12;         // col tile 0..11

    const int tid  = threadIdx.x;
    const int wave = tid >> 6;
    const int lane = tid & 63;
    const int l15  = lane & 15;
    const int hi   = lane >> 4;

    const int brow = bx * 64;
    const int bcol = by * 64;

    #pragma unroll
    for (int i = 0; i < 8; ++i) {
        const int slot = tid + i * 256;          // 0..2047
        const int row  = slot >> 5;              // 0..63
        const int p    = slot & 31;              // 16B chunk within 512B row
        const int goff = ((p ^ (row & 7)) << 3); // elements (16B = 8 shorts)
        gl_lds16(Xb  + (size_t)(brow + row) * DIM + goff, Ash + slot * 8);
        gl_lds16(Wcb + (size_t)(bcol + row) * DIM + goff, Bsh + slot * 8);
    }
    __syncthreads();

    f32x4 acc[4];
    #pragma unroll
    for (int c = 0; c < 4; ++c) acc[c] = (f32x4){0.f, 0.f, 0.f, 0.f};

    const int arow = wave * 16 + l15;
    #pragma unroll
    for (int kk = 0; kk < 8; ++kk) {
        const int ch = kk * 4 + hi;              // 16B chunk index 0..31
        bf16x8 a = *(const bf16x8*)((char*)Ash + arow * 512 + ((ch ^ (arow & 7)) << 4));
        #pragma unroll
        for (int c = 0; c < 4; ++c) {
            const int bro = c * 16 + l15;
            bf16x8 b = *(const bf16x8*)((char*)Bsh + bro * 512 + ((ch ^ (bro & 7)) << 4));
            acc[c] = __builtin_amdgcn_mfma_f32_16x16x32_bf16(a, b, acc[c], 0, 0, 0);
        }
    }

    const int z = by >> 2;
    const float* Bi = (z == 0) ? Bq : (z == 1) ? Bk : Bv;
    const float scale = (z == 0) ? 0.17677669529663687f : 1.0f;
    #pragma unroll
    for (int c = 0; c < 4; ++c) {
        const int ocol = bcol + c * 16 + l15;
        const float bvv = Bi[ocol & 255];
        #pragma unroll
        for (int r = 0; r < 4; ++r) {
            const int row = brow + wave * 16 + hi * 4 + r;
            Y[(size_t)row * GDIM + ocol] = f2bf((acc[c][r] + bvv) * scale);
        }
    }
}

// ---------------- Neighborhood attention (round-9 inner loops) --------------
// 1-D grid 784 = 8 XCDs x 98: each XCD owns a contiguous band of 14 image
// rows (one bz half) -> K/V gathers hit the XCD-local L2 (~1.7MB working set).
__global__ __launch_bounds__(256, 3) void nattn_kernel(
    const short* __restrict__ Yg,            // [NPIX][768] bf16: Q|K|V
    const float* __restrict__ rpb,           // [8][13][13] f32
    float* __restrict__ out)                 // [NPIX][256] f32
{
    __shared__ short VshT[128 * UKP];            // 32768 B: [d'][key], byte ^= ((d'&7)<<4)
    __shared__ short Psh[4 * 16 * UKP];          // 16384 B: byte ^= (pix<<4)
    __shared__ __align__(16) short rpbs[8 * 169]; // 2704 B bf16

    // XCD-aware bijective swizzle: 784 = 8 * 98; flat = (bz, ip, hg, jt)
    const int id   = blockIdx.x;
    const int flat = (id & 7) * 98 + (id >> 3);
    const int bz   = flat / 392;
    int rem        = flat - bz * 392;        // 0..391
    const int ip   = rem / 14;               // 0..27
    rem           -= ip * 14;
    const int hg   = rem / 7;                // 0..1
    const int jt   = rem - hg * 7;           // 0..6

    const int tid  = threadIdx.x;
    const int wv   = tid >> 6;
    const int lane = tid & 63;
    const int l15  = lane & 15;
    const int hi   = lane >> 4;

    const int i0 = 2 * ip;
    const int j0 = jt * 8;
    const int r0 = min(max(i0 - 3, 0), HW - KW);
    const int c0 = min(max(j0 - 3, 0), HW - KW);

    const int h = hg * 4 + wv;               // this wave's head

    // ---- batch-issue ALL staging global loads ------------------------------
    const int k2   = tid & 63;               // key pair index
    const int dblk = tid >> 6;               // 0..3 -> dims dblk*32..+31
    const int keyL = 2 * k2, keyR = 2 * k2 + 1;
    const int aL = keyL / 14, cL = keyL - aL * 14;
    const int aR = keyR / 14, cR = keyR - aR * 14;
    const int giL = min(r0 + aL, HW - 1), gjL = min(c0 + cL, HW - 1);
    const int giR = min(r0 + aR, HW - 1), gjR = min(c0 + cR, HW - 1);
    const short* srcL = Yg + (size_t)((bz * HW + giL) * HW + gjL) * GDIM + 512 + hg * 128 + dblk * 32;
    const short* srcR = Yg + (size_t)((bz * HW + giR) * HW + gjR) * GDIM + 512 + hg * 128 + dblk * 32;
    bf16x8 vL[4], vR[4];
    #pragma unroll
    for (int m = 0; m < 4; ++m) {
        vL[m] = (keyL < UK) ? *(const bf16x8*)(srcL + m * 8) : (bf16x8){0,0,0,0,0,0,0,0};
        vR[m] = (keyR < UK) ? *(const bf16x8*)(srcR + m * 8) : (bf16x8){0,0,0,0,0,0,0,0};
    }

    const int qpix = (bz * HW + i0 + (l15 >> 3)) * HW + j0 + (l15 & 7);
    bf16x8 aq = *(const bf16x8*)(Yg + (size_t)qpix * GDIM + h * HD + hi * 8);

    const float4* rpb4 = (const float4*)rpb;
    float4 rv0 = rpb4[tid];
    float4 rv1 = (tid < 338 - 256) ? rpb4[tid + 256] : (float4){0.f,0.f,0.f,0.f};

    // ---- LDS writes --------------------------------------------------------
    #pragma unroll
    for (int m = 0; m < 4; ++m) {
        #pragma unroll
        for (int e = 0; e < 8; ++e) {
            const int d = dblk * 32 + m * 8 + e;          // d&7 == e
            const int w = ((int)(unsigned short)vL[m][e]) | ((int)vR[m][e] << 16);
            *(int*)((char*)VshT + d * 256 + ((4 * k2) ^ (e << 4))) = w;
        }
    }
    *(short4*)(&rpbs[tid * 4]) = make_short4(f2bf(rv0.x), f2bf(rv0.y), f2bf(rv0.z), f2bf(rv0.w));
    if (tid < 338 - 256)
        *(short4*)(&rpbs[(tid + 256) * 4]) = make_short4(f2bf(rv1.x), f2bf(rv1.y), f2bf(rv1.z), f2bf(rv1.w));
    {   // zero Psh keys 112..127 (swizzled), per wave region
        const int p = (lane >> 2) & 15, m4 = lane & 3;
        const int k = UK + m4 * 4;
        char* dst = (char*)Psh + (wv * 16 + p) * 256 + ((2 * k) ^ (p << 4));
        *(int2*)dst = make_int2(0, 0);
    }
    __syncthreads();

    int iv[4], jv[4], bb[4], uai[4], ucj[4];
    #pragma unroll
    for (int r = 0; r < 4; ++r) {
        const int p = hi * 4 + r;
        iv[r] = i0 + (p >> 3);
        jv[r] = j0 + (p & 7);
        const int siv = min(max(iv[r] - 3, 0), HW - KW);
        const int sjv = min(max(jv[r] - 3, 0), HW - KW);
        bb[r]  = (r0 - iv[r] + 6) * 13 + (c0 - jv[r] + 6);
        uai[r] = siv - r0;
        ucj[r] = sjv - c0;
    }
    const f32x4 zf = {0.f, 0.f, 0.f, 0.f};

    // scores: batch-issue 7 K B-frag loads, then 7 MFMAs
    f32x4 sacc[7];
    {
        bf16x8 kb[7];
        #pragma unroll
        for (int t = 0; t < 7; ++t) {
            const int key = t * 16 + l15;
            const int a = key / 14, c = key - a * 14;
            const int gi = min(r0 + a, HW - 1), gj = min(c0 + c, HW - 1);
            kb[t] = *(const bf16x8*)(Yg + (size_t)((bz * HW + gi) * HW + gj) * GDIM +
                                     256 + h * HD + hi * 8);
        }
        #pragma unroll
        for (int t = 0; t < 7; ++t)
            sacc[t] = __builtin_amdgcn_mfma_f32_16x16x32_bf16(aq, kb[t], zf, 0, 0, 0);
    }

    // bias + mask -> sc[r][t]
    const short* rbh = rpbs + h * 169;
    int aA[7], cA[7], a13[7];
    #pragma unroll
    for (int t = 0; t < 7; ++t) {
        const int key = t * 16 + l15;
        aA[t] = key / 14;
        cA[t] = key - aA[t] * 14;
        a13[t] = aA[t] * 13 + cA[t];
    }
    float sc[4][7];
    #pragma unroll
    for (int t = 0; t < 7; ++t) {
        #pragma unroll
        for (int r = 0; r < 4; ++r) {
            const bool ok = ((unsigned)(aA[t] - uai[r]) <= 6u) &
                            ((unsigned)(cA[t] - ucj[r]) <= 6u);
            const float s = sacc[t][r] + bf2f(rbh[bb[r] + a13[t]]);
            sc[r][t] = ok ? s : -1e30f;
        }
    }

    // row max + exp + P store + sum
    float sm[4];
    #pragma unroll
    for (int r = 0; r < 4; ++r) {
        float m = sc[r][0];
        #pragma unroll
        for (int t = 1; t < 7; ++t) m = fmaxf(m, sc[r][t]);
        m = fmaxf(m, __shfl_xor(m, 1));
        m = fmaxf(m, __shfl_xor(m, 2));
        m = fmaxf(m, __shfl_xor(m, 4));
        m = fmaxf(m, __shfl_xor(m, 8));
        const int pix = hi * 4 + r;
        char* prow = (char*)Psh + (wv * 16 + pix) * 256;
        const int pswz = pix << 4;
        float s = 0.f;
        #pragma unroll
        for (int t = 0; t < 7; ++t) {
            const float e = __expf(sc[r][t] - m);
            s += e;
            const int key = t * 16 + l15;
            *(short*)(prow + ((2 * key) ^ pswz)) = f2bf(e);
        }
        s += __shfl_xor(s, 1);
        s += __shfl_xor(s, 2);
        s += __shfl_xor(s, 4);
        s += __shfl_xor(s, 8);
        sm[r] = s;
    }

    // PV: 4 ksteps x 2 dim-tiles
    const int d0 = wv * 32 + l15;
    f32x4 o0 = zf, o1 = zf;
    #pragma unroll
    for (int kk = 0; kk < 4; ++kk) {
        bf16x8 pa = *(const bf16x8*)((char*)Psh + (wv * 16 + l15) * 256 +
                                     ((kk * 64 + hi * 16) ^ (l15 << 4)));
        const int koff = (kk * 64 + hi * 16) ^ ((l15 & 7) << 4);
        bf16x8 vb0 = *(const bf16x8*)((char*)VshT + d0 * 256 + koff);
        bf16x8 vb1 = *(const bf16x8*)((char*)VshT + (d0 + 16) * 256 + koff);
        o0 = __builtin_amdgcn_mfma_f32_16x16x32_bf16(pa, vb0, o0, 0, 0, 0);
        o1 = __builtin_amdgcn_mfma_f32_16x16x32_bf16(pa, vb1, o1, 0, 0, 0);
    }

    // epilogue
    #pragma unroll
    for (int r = 0; r < 4; ++r) {
        const float inv = 1.f / sm[r];
        const int pg = (bz * HW + iv[r]) * HW + jv[r];
        out[(size_t)pg * DIM + h * HD + l15]      = o0[r] * inv;
        out[(size_t)pg * DIM + h * HD + 16 + l15] = o1[r] * inv;
    }
}

extern "C" void kernel_launch(void* const* d_in, const int* in_sizes, int n_in,
                              void* d_out, int out_size, void* d_ws, size_t ws_size,
                              hipStream_t stream) {
    const float* hs = (const float*)d_in[0];
    const float* wq = (const float*)d_in[1];
    const float* bq = (const float*)d_in[2];
    const float* wk = (const float*)d_in[3];
    const float* bk = (const float*)d_in[4];
    const float* wv = (const float*)d_in[5];
    const float* bv = (const float*)d_in[6];
    const float* rpb = (const float*)d_in[7];

    short* Y   = (short*)d_ws;                       // [6272][768]
    short* Xb  = Y + (size_t)NPIX * GDIM;            // [6272][256]
    short* Wcb = Xb + (size_t)NX;                    // [768][256]

    cvt_kernel<<<(NX + 3 * NW) / (256 * 8), 256, 0, stream>>>(hs, wq, wk, wv, Xb, Wcb);

    proj_kernel<<<1176, 256, 0, stream>>>(Xb, Wcb, bq, bk, bv, Y);

    nattn_kernel<<<784, 256, 0, stream>>>(Y, rpb, (float*)d_out);
}